// Round 5
// baseline (430.800 us; speedup 1.0000x reference)
//
#include <hip/hip_runtime.h>
#include <math.h>

// ---------------------------------------------------------------------------
// out[b][s] = <v_b| I_{2^s} (x) W (x) I |v_b> / <v_b|v_b>,  s=0..12
// R11 = R8 design with STATIC 128 KB LDS + compile-time unit dispatch.
// R9/R10 post-mortem: extern __shared__ (dynamic) LDS is invisible to the
// backend's occupancy heuristic (LDS_Block_Size showed 1024 B) -> it budgeted
// for 8 waves/EU -> pressure-minimized to 64 VGPRs, spilling ~6 dwords/thread
// per chunk (92 MB scratch writes, 157 us). Neither launch_bounds(,4) nor
// amdgpu_waves_per_eu(1,4) changed codegen (both bounds already satisfied by
// 8 waves/EU). Declaring the 128 KB tile as STATIC __shared__ makes the
// 1-block/CU occupancy visible -> native 128-VGPR budget -> no spills.
// Also: unit dispatch now uses literal (c0,c1) per wave so the MFMA loops
// fully unroll with immediate LDS offsets (runtime 'half' blocked unrolling).
// Design (unchanged from R8):
//  - single read: one 1024-thread block per 2 rows (256 blocks, 1 block/CU),
//    row streamed in 8x8KB fp32 chunks -> fp16 in 128 KB LDS (full row).
//  - lgkmcnt-only barrier keeps next-chunk global prefetch in flight (T4).
//  - Gram accumulators persist across the row's 8 chunks; contract +
//    wave_sum + atomicAdd once per row.
//  - full-row windows s=0 and s=1,2 (fused 32x32 Gram) at row end.
// HBM traffic = 128 MiB exactly (one fp32 read).
// ws layout (floats): [0..256) W row-major; [256..) acc[row*14+s], slot13=sumsq
// ---------------------------------------------------------------------------

typedef _Float16 f16x8 __attribute__((ext_vector_type(8)));
typedef float f32x4 __attribute__((ext_vector_type(4)));
typedef float f32x16 __attribute__((ext_vector_type(16)));
#define MFMAH(a, b, c) __builtin_amdgcn_mfma_f32_16x16x32_f16((a), (b), (c), 0, 0, 0)
#define MFMA32(a, b, c) __builtin_amdgcn_mfma_f32_32x32x16_f16((a), (b), (c), 0, 0, 0)

// LDS-only barrier: waits DS ops, leaves global loads in flight.
#define BAR_LDS() asm volatile("s_waitcnt lgkmcnt(0)\n\ts_barrier" ::: "memory")

union Frag { _Float16 h[8]; f16x8 v; uint2 q[2]; unsigned int w[4]; };

__device__ __forceinline__ int swz(int g) { return g ^ (g >> 5); }

__device__ __forceinline__ float wave_sum(float x) {
    #pragma unroll
    for (int off = 32; off > 0; off >>= 1) x += __shfl_down(x, off, 64);
    return x;
}

// ------------------------- setup: build W on device -------------------------
using c2 = float2;
__device__ __forceinline__ c2 cmul(c2 a, c2 b) {
    return make_float2(a.x * b.x - a.y * b.y, a.x * b.y + a.y * b.x);
}
__device__ __forceinline__ c2 cadd(c2 a, c2 b) { return make_float2(a.x + b.x, a.y + b.y); }

__device__ __forceinline__ c2 kelem(const c2 u[4][2][2], int i, int j) {
    c2 p = cmul(u[0][(i >> 3) & 1][(j >> 3) & 1], u[1][(i >> 2) & 1][(j >> 2) & 1]);
    p = cmul(p, u[2][(i >> 1) & 1][(j >> 1) & 1]);
    p = cmul(p, u[3][i & 1][j & 1]);
    return p;
}
__device__ __forceinline__ int fperm(int x) {
    int b3 = (x >> 3) & 1, b2 = (x >> 2) & 1, b1 = (x >> 1) & 1, b0 = x & 1;
    b2 ^= b3; b1 ^= b2; b0 ^= b1; b3 ^= b0;
    return (b3 << 3) | (b2 << 2) | (b1 << 1) | b0;
}

__global__ __launch_bounds__(256) void setup_kernel(const float* __restrict__ weight,
                                                    float* __restrict__ ws) {
    __shared__ c2 ush[3][4][2][2];
    __shared__ c2 A[256], B[256];
    const int t = threadIdx.x;

    if (t < 12) {
        const int r = t / 4, q = t % 4;
        const float a = weight[12 * r + 3 * q + 0];
        const float b = weight[12 * r + 3 * q + 1];
        const float c = weight[12 * r + 3 * q + 2];
        const float ca = cosf(0.5f * a), sa = sinf(0.5f * a);
        const float cc = cosf(0.5f * c), sc = sinf(0.5f * c);
        const c2 e = make_float2(cosf(0.5f * b), -sinf(0.5f * b));
        const c2 eb = make_float2(e.x, -e.y);
        ush[r][q][0][0] = make_float2(cc * ca * e.x - sc * sa * eb.x, cc * ca * e.y - sc * sa * eb.y);
        ush[r][q][0][1] = make_float2(-cc * sa * e.x - sc * ca * eb.x, -cc * sa * e.y - sc * ca * eb.y);
        ush[r][q][1][0] = make_float2(sc * ca * e.x + cc * sa * eb.x, sc * ca * e.y + cc * sa * eb.y);
        ush[r][q][1][1] = make_float2(-sc * sa * e.x + cc * ca * eb.x, -sc * sa * e.y + cc * ca * eb.y);
    }
    __syncthreads();

    const int i = t >> 4, j = t & 15;
    A[t] = kelem(ush[0], i, j);
    __syncthreads();
    B[fperm(i) * 16 + j] = A[t];
    __syncthreads();
    {
        c2 acc = make_float2(0.f, 0.f);
        #pragma unroll
        for (int k = 0; k < 16; ++k) acc = cadd(acc, cmul(kelem(ush[1], i, k), B[k * 16 + j]));
        __syncthreads();
        A[t] = acc;
    }
    __syncthreads();
    B[fperm(i) * 16 + j] = A[t];
    __syncthreads();
    {
        c2 acc = make_float2(0.f, 0.f);
        #pragma unroll
        for (int k = 0; k < 16; ++k) acc = cadd(acc, cmul(kelem(ush[2], i, k), B[k * 16 + j]));
        __syncthreads();
        A[t] = acc;
    }
    __syncthreads();
    {
        float wr = 0.f;
        #pragma unroll
        for (int k = 0; k < 16; ++k) {
            const c2 a = A[k * 16 + i];
            const c2 b = A[(k ^ 15) * 16 + j];
            wr += a.x * b.x + a.y * b.y;
        }
        ws[t] = wr;
    }
    for (int z = t; z < 512 * 14; z += 256) ws[256 + z] = 0.f;
}

// ----------------------------- unit helpers ---------------------------------

__device__ __forceinline__ void contract16(const float* __restrict__ Wl, const f32x4& acc,
                                           int i, int h, int l, float* dst) {
    const float4 wr = *(const float4*)&Wl[(i << 4) + (h << 2)];
    float q = wr.x * acc[0] + wr.y * acc[1] + wr.z * acc[2] + wr.w * acc[3];
    q = wave_sum(q);
    if (l == 0) atomicAdd(dst, q);
}

// Epilogue of a fused 32x32 Gram over a 5-bit window-union.
__device__ __forceinline__ void pair_contract(const f32x16& acc, const float* __restrict__ Wl,
                                              int Jp, int h2, int l,
                                              float* dqa, float* dqb) {
    float qa = 0.f, qb = 0.f;
    #pragma unroll
    for (int r2 = 0; r2 < 8; ++r2) {
        const int r = 2 * r2;
        const int J = (r & 3) + 8 * (r >> 2) + 4 * h2;
        qa += Wl[((J >> 1) << 4) + (Jp >> 1)] * ((Jp & 1) ? acc[r + 1] : acc[r]);
    }
    #pragma unroll
    for (int r = 0; r < 8; ++r) {
        const int J = (r & 3) + 8 * (r >> 2) + 4 * h2;
        qb += Wl[((J & 15) << 4) + (Jp & 15)] * ((Jp & 16) ? acc[r + 8] : acc[r]);
    }
    qa = wave_sum(qa);
    qb = wave_sum(qb);
    if (l == 0) { atomicAdd(dqa, qa); atomicAdd(dqb, qb); }
}

// Per-chunk Gram updates (accumulate into persistent acc; contract at row end)
template <int S, int C0, int C1>
__device__ __forceinline__ void pair_unit(const unsigned short* __restrict__ sh,
                                          int l, f32x16& acc) {
    const int Jp = l & 31, h2 = l >> 5;
    #pragma unroll
    for (int cc = C0; cc < C1; ++cc) {
        int e0;
        if (S == 3)      e0 = (Jp << 8) + (cc << 4) + (h2 << 3);
        else if (S == 5) e0 = ((cc >> 2) << 11) + (Jp << 6) + ((cc & 3) << 4) + (h2 << 3);
        else             e0 = (cc << 9) + (Jp << 4) + (h2 << 3);
        const f16x8 f = *(const f16x8*)&sh[swz(e0 >> 3) << 3];
        acc = MFMA32(f, f, acc);
    }
}

template <int C0, int C1>
__device__ __forceinline__ void unit9(const unsigned short* __restrict__ sh,
                                      int i, int h, f32x4& acc) {
    #pragma unroll
    for (int cc = C0; cc < C1; ++cc) {
        const int e0 = ((4 * cc + h) << 7) + (i << 3);
        const f16x8 f = *(const f16x8*)&sh[swz(e0 >> 3) << 3];
        acc = MFMAH(f, f, acc);
    }
}

template <int C0, int C1>
__device__ __forceinline__ void unit10(const unsigned short* __restrict__ sh,
                                       int i, int h, f32x4& acc) {
    #pragma unroll
    for (int cc = C0; cc < C1; ++cc) {
        const int a0 = 8 * cc + 2 * h;
        const int ea = a0 * 64 + 4 * i;
        const int eb = ea + 64;
        Frag fr;
        fr.q[0] = *(const uint2*)&sh[(swz(ea >> 3) << 3) + (ea & 7)];
        fr.q[1] = *(const uint2*)&sh[(swz(eb >> 3) << 3) + (eb & 7)];
        acc = MFMAH(fr.v, fr.v, acc);
    }
}

template <int C0, int C1>
__device__ __forceinline__ void unit11(const unsigned short* __restrict__ sh,
                                       int i, int h, f32x4& acc) {
    #pragma unroll
    for (int cc = C0; cc < C1; ++cc) {
        Frag fr;
        #pragma unroll
        for (int p = 0; p < 4; ++p) {
            const int ap = 16 * cc + 4 * h + p;
            const int e = ap * 32 + 2 * i;
            fr.w[p] = *(const unsigned int*)&sh[(swz(e >> 3) << 3) + (e & 7)];
        }
        acc = MFMAH(fr.v, fr.v, acc);
    }
}

// s=12: window = element bits 0..3 within a chunk (scalar u16 gather).
template <int C0, int C1>
__device__ __forceinline__ void unitW0(const unsigned short* __restrict__ sh,
                                       int i, int h, f32x4& acc) {
    #pragma unroll
    for (int cc = C0; cc < C1; ++cc) {
        Frag fr;
        #pragma unroll
        for (int p = 0; p < 8; ++p) {
            const int e = i + ((cc * 32 + h * 8 + p) << 4);
            fr.h[p] = *(const _Float16*)&sh[(swz(e >> 3) << 3) + (e & 7)];
        }
        acc = MFMAH(fr.v, fr.v, acc);
    }
}

// ------------------------------ fused main ----------------------------------
// 256 blocks x 1024 threads; block b owns rows 2b, 2b+1. Full row (fp16) lives
// in 128 KB STATIC LDS as 8 chunks of 8192 elems. Static allocation makes the
// 1-block/CU occupancy visible to the register allocator -> 128-VGPR budget.
__global__ __launch_bounds__(1024)
__attribute__((amdgpu_waves_per_eu(1, 4)))
void main_kernel(const float* __restrict__ v,
                 const float* __restrict__ ws,
                 float* __restrict__ accg) {
    __shared__ __align__(16) unsigned short sh16[65536];   // 128 KB static
    __shared__ float Wl[256];
    const int t = threadIdx.x;
    const int l = t & 63, wv = t >> 6;
    const int i = l & 15, h = l >> 4;
    const int J = l & 31, h2 = l >> 5;
    if (t < 256) Wl[t] = ws[t];

    const float4* __restrict__ base = (const float4*)(v + ((size_t)blockIdx.x << 17));
    float* accrow = accg + (size_t)(2 * blockIdx.x) * 14;

    // prefetch chunk 0 (row 0)
    float4 a0 = base[2 * t], a1 = base[2 * t + 1];
    float ss = 0.f;

    // persistent Gram accumulators (contracted once per row)
    f32x16 accP;
    f32x4 accS;
    #pragma unroll
    for (int r = 0; r < 16; ++r) accP[r] = 0.f;
    #pragma unroll
    for (int r = 0; r < 4; ++r) accS[r] = 0.f;

    for (int k = 0; k < 16; ++k) {
        // issue next chunk's loads BEFORE consuming current (stay in flight
        // across the lgkm-only barrier below)
        float4 b0, b1;
        const bool more = (k < 15);
        if (more) {
            b0 = base[(k + 1) * 2048 + 2 * t];
            b1 = base[(k + 1) * 2048 + 2 * t + 1];
        }

        // consume current chunk: sumsq + cvt + LDS write (granule t -> swz(t))
        ss = fmaf(a0.x, a0.x, ss); ss = fmaf(a0.y, a0.y, ss);
        ss = fmaf(a0.z, a0.z, ss); ss = fmaf(a0.w, a0.w, ss);
        ss = fmaf(a1.x, a1.x, ss); ss = fmaf(a1.y, a1.y, ss);
        ss = fmaf(a1.z, a1.z, ss); ss = fmaf(a1.w, a1.w, ss);
        Frag fr;
        fr.h[0] = (_Float16)a0.x; fr.h[1] = (_Float16)a0.y;
        fr.h[2] = (_Float16)a0.z; fr.h[3] = (_Float16)a0.w;
        fr.h[4] = (_Float16)a1.x; fr.h[5] = (_Float16)a1.y;
        fr.h[6] = (_Float16)a1.z; fr.h[7] = (_Float16)a1.w;
        const int c = k & 7;
        *(f16x8*)&sh16[(c << 13) + (swz(t) << 3)] = fr.v;
        BAR_LDS();   // chunk c visible; global prefetch STAYS in flight

        // chunk-local Gram updates s=3..12 (16 waves, 16 compile-time tasks)
        const unsigned short* sh = &sh16[c << 13];
        if      (wv == 0)  pair_unit<3, 0, 8 >(sh, l, accP);
        else if (wv == 1)  pair_unit<3, 8, 16>(sh, l, accP);
        else if (wv == 2)  pair_unit<5, 0, 8 >(sh, l, accP);
        else if (wv == 3)  pair_unit<5, 8, 16>(sh, l, accP);
        else if (wv == 4)  pair_unit<7, 0, 8 >(sh, l, accP);
        else if (wv == 5)  pair_unit<7, 8, 16>(sh, l, accP);
        else if (wv == 6)  unit9 <0, 8 >(sh, i, h, accS);
        else if (wv == 7)  unit9 <8, 16>(sh, i, h, accS);
        else if (wv == 8)  unit10<0, 8 >(sh, i, h, accS);
        else if (wv == 9)  unit10<8, 16>(sh, i, h, accS);
        else if (wv == 10) unit11<0, 8 >(sh, i, h, accS);
        else if (wv == 11) unit11<8, 16>(sh, i, h, accS);
        else if (wv == 12) unitW0<0, 4 >(sh, i, h, accS);
        else if (wv == 13) unitW0<4, 8 >(sh, i, h, accS);
        else if (wv == 14) unitW0<8, 12>(sh, i, h, accS);
        else               unitW0<12, 16>(sh, i, h, accS);

        if (c == 7) {
            // ---- row end: contract the accumulated chunk Grams
            if (wv < 6) {
                const int S = 3 + ((wv >> 1) << 1);          // 3,5,7
                pair_contract(accP, Wl, J, h2, l, &accrow[S], &accrow[S + 1]);
                #pragma unroll
                for (int r = 0; r < 16; ++r) accP[r] = 0.f;
            } else {
                const int sidx = (wv < 8) ? 9 : (wv < 10) ? 10 : (wv < 12) ? 11 : 12;
                contract16(Wl, accS, i, h, l, &accrow[sidx]);
                #pragma unroll
                for (int r = 0; r < 4; ++r) accS[r] = 0.f;
            }

            // ---- full-row units (next row's chunk-0 loads already in flight)
            // s=0: window = bits 12..15
            {
                f32x4 acc = {0.f, 0.f, 0.f, 0.f};
                #pragma unroll
                for (int j = 0; j < 8; ++j) {
                    const int cc = (wv << 3) + j;               // 0..127
                    const int e = (i << 12) + cc * 32 + h * 8;
                    const f16x8 f = *(const f16x8*)
                        &sh16[((e >> 13) << 13) + (swz((e & 8191) >> 3) << 3)];
                    acc = MFMAH(f, f, acc);
                }
                contract16(Wl, acc, i, h, l, &accrow[0]);
            }
            // s=1,2 fused: 32x32 Gram over union = bits 10..14; K = bits {0..9,15}
            {
                f32x16 acc;
                #pragma unroll
                for (int r = 0; r < 16; ++r) acc[r] = 0.f;
                #pragma unroll
                for (int j = 0; j < 8; ++j) {
                    const int cc = (wv << 3) + j;               // 0..127
                    const int kg = cc * 16 + h2 * 8;            // 11-bit K index
                    const int e = (J << 10) + (kg & 1023) + ((kg >> 10) << 15);
                    const f16x8 f = *(const f16x8*)
                        &sh16[((e >> 13) << 13) + (swz((e & 8191) >> 3) << 3)];
                    acc = MFMA32(f, f, acc);
                }
                pair_contract(acc, Wl, J, h2, l, &accrow[1], &accrow[2]);
            }
            {
                const float s2 = wave_sum(ss);
                if (l == 0) atomicAdd(&accrow[13], s2);
                ss = 0.f;
            }
            BAR_LDS();   // all reads of this row done before overwrite
            accrow += 14;
        }
        if (more) { a0 = b0; a1 = b1; }
    }
}

__global__ __launch_bounds__(256) void finalize_kernel(const float* __restrict__ acc,
                                                       float* __restrict__ out) {
    const int idx = blockIdx.x * 256 + threadIdx.x;
    if (idx < 512 * 13) {
        const int row = idx / 13, s = idx % 13;
        out[idx] = acc[row * 14 + s] / acc[row * 14 + 13];
    }
}

extern "C" void kernel_launch(void* const* d_in, const int* in_sizes, int n_in,
                              void* d_out, int out_size, void* d_ws, size_t ws_size,
                              hipStream_t stream) {
    const float* vb = (const float*)d_in[0];
    const float* wt = (const float*)d_in[1];
    float* out = (float*)d_out;
    float* ws = (float*)d_ws;
    float* acc = ws + 256;

    setup_kernel<<<1, 256, 0, stream>>>(wt, ws);
    main_kernel<<<256, 1024, 0, stream>>>(vb, ws, acc);
    finalize_kernel<<<26, 256, 0, stream>>>(acc, out);
}

// Round 6
// 197.245 us; speedup vs baseline: 2.1841x; 2.1841x over previous
//
#include <hip/hip_runtime.h>
#include <math.h>

// ---------------------------------------------------------------------------
// out[b][s] = <v_b| I_{2^s} (x) W (x) I |v_b> / <v_b|v_b>,  s=0..12
// R12 = R0 (proven 194.6us two-pass structure) + s=12 moved from the col path
// into the contiguous path (unitW0, verified in R7-R11), col path rebalanced:
//   contiguous (unit 0..7): s=3..12 + sumsq   (was s=3..11 + sumsq)
//   col        (unit 8..15): s=0,1,2          (was s=0,1,2,12)
// Col critical wave drops 20->16 MFMA iters; s=2 split evenly across w2/w3.
// R7-R11 post-mortem: the 1024-thread single-read megablock is pinned at 64
// VGPRs by the allocator regardless of launch_bounds/waves_per_eu/static-LDS
// -> persistent-accumulator design spills (92-429 MB scratch) -> 157-330us.
// Reverting to the spill-free 256-thread structure.
// R6: blockIdx remap so all 16 blocks of one row share idx%8 (same XCD under
// round-robin dispatch) and dispatch adjacently -> col pass re-reads the row
// from that XCD's L2 instead of L3/HBM.
// ws layout (floats): [0..256) W row-major; [256..) acc[row*14+s], slot13=sumsq
// ---------------------------------------------------------------------------

typedef _Float16 f16x8 __attribute__((ext_vector_type(8)));
typedef float f32x4 __attribute__((ext_vector_type(4)));
typedef float f32x16 __attribute__((ext_vector_type(16)));
#define MFMAH(a, b, c) __builtin_amdgcn_mfma_f32_16x16x32_f16((a), (b), (c), 0, 0, 0)
#define MFMA32(a, b, c) __builtin_amdgcn_mfma_f32_32x32x16_f16((a), (b), (c), 0, 0, 0)

union H4 { _Float16 h[4]; uint2 q; };
union Frag { _Float16 h[8]; f16x8 v; uint2 q[2]; unsigned int w[4]; };

__device__ __forceinline__ int swz(int g) { return g ^ (g >> 5); }

__device__ __forceinline__ float wave_sum(float x) {
    #pragma unroll
    for (int off = 32; off > 0; off >>= 1) x += __shfl_down(x, off, 64);
    return x;
}

// ------------------------- setup: build W on device -------------------------
using c2 = float2;
__device__ __forceinline__ c2 cmul(c2 a, c2 b) {
    return make_float2(a.x * b.x - a.y * b.y, a.x * b.y + a.y * b.x);
}
__device__ __forceinline__ c2 cadd(c2 a, c2 b) { return make_float2(a.x + b.x, a.y + b.y); }

__device__ __forceinline__ c2 kelem(const c2 u[4][2][2], int i, int j) {
    c2 p = cmul(u[0][(i >> 3) & 1][(j >> 3) & 1], u[1][(i >> 2) & 1][(j >> 2) & 1]);
    p = cmul(p, u[2][(i >> 1) & 1][(j >> 1) & 1]);
    p = cmul(p, u[3][i & 1][j & 1]);
    return p;
}
__device__ __forceinline__ int fperm(int x) {
    int b3 = (x >> 3) & 1, b2 = (x >> 2) & 1, b1 = (x >> 1) & 1, b0 = x & 1;
    b2 ^= b3; b1 ^= b2; b0 ^= b1; b3 ^= b0;
    return (b3 << 3) | (b2 << 2) | (b1 << 1) | b0;
}

__global__ __launch_bounds__(256) void setup_kernel(const float* __restrict__ weight,
                                                    float* __restrict__ ws) {
    __shared__ c2 ush[3][4][2][2];
    __shared__ c2 A[256], B[256];
    const int t = threadIdx.x;

    if (t < 12) {
        const int r = t / 4, q = t % 4;
        const float a = weight[12 * r + 3 * q + 0];
        const float b = weight[12 * r + 3 * q + 1];
        const float c = weight[12 * r + 3 * q + 2];
        const float ca = cosf(0.5f * a), sa = sinf(0.5f * a);
        const float cc = cosf(0.5f * c), sc = sinf(0.5f * c);
        const c2 e = make_float2(cosf(0.5f * b), -sinf(0.5f * b));
        const c2 eb = make_float2(e.x, -e.y);
        ush[r][q][0][0] = make_float2(cc * ca * e.x - sc * sa * eb.x, cc * ca * e.y - sc * sa * eb.y);
        ush[r][q][0][1] = make_float2(-cc * sa * e.x - sc * ca * eb.x, -cc * sa * e.y - sc * ca * eb.y);
        ush[r][q][1][0] = make_float2(sc * ca * e.x + cc * sa * eb.x, sc * ca * e.y + cc * sa * eb.y);
        ush[r][q][1][1] = make_float2(-sc * sa * e.x + cc * ca * eb.x, -sc * sa * e.y + cc * ca * eb.y);
    }
    __syncthreads();

    const int i = t >> 4, j = t & 15;
    A[t] = kelem(ush[0], i, j);
    __syncthreads();
    B[fperm(i) * 16 + j] = A[t];
    __syncthreads();
    {
        c2 acc = make_float2(0.f, 0.f);
        #pragma unroll
        for (int k = 0; k < 16; ++k) acc = cadd(acc, cmul(kelem(ush[1], i, k), B[k * 16 + j]));
        __syncthreads();
        A[t] = acc;
    }
    __syncthreads();
    B[fperm(i) * 16 + j] = A[t];
    __syncthreads();
    {
        c2 acc = make_float2(0.f, 0.f);
        #pragma unroll
        for (int k = 0; k < 16; ++k) acc = cadd(acc, cmul(kelem(ush[2], i, k), B[k * 16 + j]));
        __syncthreads();
        A[t] = acc;
    }
    __syncthreads();
    {
        float wr = 0.f;
        #pragma unroll
        for (int k = 0; k < 16; ++k) {
            const c2 a = A[k * 16 + i];
            const c2 b = A[(k ^ 15) * 16 + j];
            wr += a.x * b.x + a.y * b.y;
        }
        ws[t] = wr;
    }
    for (int z = t; z < 512 * 14; z += 256) ws[256 + z] = 0.f;
}

// ----------------------------- unit helpers ---------------------------------

__device__ __forceinline__ void contract16(const float* __restrict__ Wl, const f32x4& acc,
                                           int i, int h, int l, float* dst) {
    const float4 wr = *(const float4*)&Wl[(i << 4) + (h << 2)];
    float q = wr.x * acc[0] + wr.y * acc[1] + wr.z * acc[2] + wr.w * acc[3];
    q = wave_sum(q);
    if (l == 0) atomicAdd(dst, q);
}

// Paired starts (S, S+1), S in {3,5,7}: one 32x32x16 Gram over J = bits
// (11-S..15-S). C/D: col = lane&31, row = (reg&3)+8*(reg>>2)+4*(lane>>5).
template <int S>
__device__ __forceinline__ void pair_unit(const unsigned short* __restrict__ sh16,
                                          const float* __restrict__ Wl,
                                          int l, float* accrow) {
    const int Jp = l & 31, h2 = l >> 5;
    f32x16 acc = {0.f, 0.f, 0.f, 0.f, 0.f, 0.f, 0.f, 0.f,
                  0.f, 0.f, 0.f, 0.f, 0.f, 0.f, 0.f, 0.f};
    #pragma unroll
    for (int cc = 0; cc < 16; ++cc) {
        int e0;
        if (S == 3)      e0 = (Jp << 8) + (cc << 4) + (h2 << 3);
        else if (S == 5) e0 = ((cc >> 2) << 11) + (Jp << 6) + ((cc & 3) << 4) + (h2 << 3);
        else             e0 = (cc << 9) + (Jp << 4) + (h2 << 3);
        const f16x8 f = *(const f16x8*)&sh16[swz(e0 >> 3) << 3];
        acc = MFMA32(f, f, acc);
    }
    float qa = 0.f, qb = 0.f;
    #pragma unroll
    for (int r2 = 0; r2 < 8; ++r2) {
        const int r = 2 * r2;
        const int J = (r & 3) + 8 * (r >> 2) + 4 * h2;
        const float w = Wl[((J >> 1) << 4) + (Jp >> 1)];
        qa += w * ((Jp & 1) ? acc[r + 1] : acc[r]);
    }
    #pragma unroll
    for (int r = 0; r < 8; ++r) {
        const int J = (r & 3) + 8 * (r >> 2) + 4 * h2;
        const float w = Wl[((J & 15) << 4) + (Jp & 15)];
        qb += w * ((Jp & 16) ? acc[r + 8] : acc[r]);
    }
    qa = wave_sum(qa);
    qb = wave_sum(qb);
    if (l == 0) { atomicAdd(&accrow[S], qa); atomicAdd(&accrow[S + 1], qb); }
}

__device__ __forceinline__ void unit9(const unsigned short* __restrict__ sh16,
                                      const float* __restrict__ Wl,
                                      int i, int h, int l, float* accrow) {
    f32x4 acc = {0.f, 0.f, 0.f, 0.f};
    #pragma unroll
    for (int cc = 0; cc < 16; ++cc) {
        const int e0 = ((4 * cc + h) << 7) + (i << 3);
        const f16x8 f = *(const f16x8*)&sh16[swz(e0 >> 3) << 3];
        acc = MFMAH(f, f, acc);
    }
    contract16(Wl, acc, i, h, l, &accrow[9]);
}

__device__ __forceinline__ void unit10(const unsigned short* __restrict__ sh16,
                                       const float* __restrict__ Wl,
                                       int i, int h, int l, int c0, int c1, float* accrow) {
    f32x4 acc = {0.f, 0.f, 0.f, 0.f};
    #pragma unroll
    for (int cc = c0; cc < c1; ++cc) {
        const int a0 = 8 * cc + 2 * h;
        const int ea = a0 * 64 + 4 * i;
        const int eb = ea + 64;
        Frag fr;
        fr.q[0] = *(const uint2*)&sh16[(swz(ea >> 3) << 3) + (ea & 7)];
        fr.q[1] = *(const uint2*)&sh16[(swz(eb >> 3) << 3) + (eb & 7)];
        acc = MFMAH(fr.v, fr.v, acc);
    }
    contract16(Wl, acc, i, h, l, &accrow[10]);
}

__device__ __forceinline__ void unit11(const unsigned short* __restrict__ sh16,
                                       const float* __restrict__ Wl,
                                       int i, int h, int l, int c0, int c1, float* accrow) {
    f32x4 acc = {0.f, 0.f, 0.f, 0.f};
    #pragma unroll
    for (int cc = c0; cc < c1; ++cc) {
        Frag fr;
        #pragma unroll
        for (int p = 0; p < 4; ++p) {
            const int ap = 16 * cc + 4 * h + p;
            const int e = ap * 32 + 2 * i;
            fr.w[p] = *(const unsigned int*)&sh16[(swz(e >> 3) << 3) + (e & 7)];
        }
        acc = MFMAH(fr.v, fr.v, acc);
    }
    contract16(Wl, acc, i, h, l, &accrow[11]);
}

// s=12 in the CONTIGUOUS path: window = element bits 0..3 of the 8192-seg
// (J=i=bits0..3, K=cc*32+h*8+p=bits4..12). Seg-partial Gram accumulates over
// segs by linearity (atomicAdd). Verified component (R7-R11 all passed).
__device__ __forceinline__ void unitW0(const unsigned short* __restrict__ sh16,
                                       const float* __restrict__ Wl,
                                       int i, int h, int l, int c0, int c1, float* accrow) {
    f32x4 acc = {0.f, 0.f, 0.f, 0.f};
    #pragma unroll
    for (int cc = c0; cc < c1; ++cc) {
        Frag fr;
        #pragma unroll
        for (int p = 0; p < 8; ++p) {
            const int e = i + ((cc * 32 + h * 8 + p) << 4);
            fr.h[p] = *(const _Float16*)&sh16[(swz(e >> 3) << 3) + (e & 7)];
        }
        acc = MFMAH(fr.v, fr.v, acc);
    }
    contract16(Wl, acc, i, h, l, &accrow[12]);
}

// ------------------------------ fused main ----------------------------------
// Block remap: blockIdx = (row&7) + 8*(unit + 16*(row>>3)), unit 0..15.
// unit 0..7  -> contiguous tile (seg = unit), s = 3..12 + sumsq
// unit 8..15 -> col-major tile (c0 = (unit-8)*64), s = 0,1,2
// All 16 blocks of a row share idx%8 -> same XCD; adjacent dispatch -> the
// col read of the row hits that XCD's L2.
__global__ __launch_bounds__(256, 5) void main_kernel(const float* __restrict__ v,
                                                      const float* __restrict__ ws,
                                                      float* __restrict__ accg) {
    __shared__ unsigned short sh16[8192];   // fp16 tile (both paths, 16 KB)
    __shared__ float Wl[256];
    const int t = threadIdx.x;
    const int l = t & 63, wv = t >> 6;
    const int i = l & 15, h = l >> 4;
    Wl[t] = ws[t];

    const int bi = blockIdx.x;
    const int g = bi >> 3;
    const int unit = g & 15;
    const int row = ((g >> 4) << 3) | (bi & 7);
    float* accrow = &accg[row * 14];

    if (unit < 8) {
        // ---------------- contiguous path: s = 3..12 ----------------
        const int seg = unit;
        const float4* b4 = (const float4*)(v + ((size_t)row << 16) + (seg << 13));

        float ss = 0.f;
        #pragma unroll
        for (int m = 0; m < 8; ++m) {
            const float4 d = b4[m * 256 + t];
            ss = fmaf(d.x, d.x, ss); ss = fmaf(d.y, d.y, ss);
            ss = fmaf(d.z, d.z, ss); ss = fmaf(d.w, d.w, ss);
            H4 p;
            p.h[0] = (_Float16)d.x; p.h[1] = (_Float16)d.y;
            p.h[2] = (_Float16)d.z; p.h[3] = (_Float16)d.w;
            const int e0 = (m * 256 + t) * 4;
            const int idx = (swz(e0 >> 3) << 3) + (e0 & 7);
            *(uint2*)&sh16[idx] = p.q;
        }
        {
            const float s2 = wave_sum(ss);
            if (l == 0) atomicAdd(&accrow[13], s2);
        }
        __syncthreads();

        // static cost-balanced schedule (+4 cc of s=12 per wave)
        if (wv == 0) {
            pair_unit<3>(sh16, Wl, l, accrow);
            unit10(sh16, Wl, i, h, l, 0, 8, accrow);
            unitW0(sh16, Wl, i, h, l, 0, 4, accrow);
        } else if (wv == 1) {
            pair_unit<5>(sh16, Wl, l, accrow);
            unit10(sh16, Wl, i, h, l, 8, 16, accrow);
            unitW0(sh16, Wl, i, h, l, 4, 8, accrow);
        } else if (wv == 2) {
            pair_unit<7>(sh16, Wl, l, accrow);
            unit11(sh16, Wl, i, h, l, 0, 8, accrow);
            unitW0(sh16, Wl, i, h, l, 8, 12, accrow);
        } else {
            unit9(sh16, Wl, i, h, l, accrow);
            unit11(sh16, Wl, i, h, l, 8, 16, accrow);
            unitW0(sh16, Wl, i, h, l, 12, 16, accrow);
        }
    } else {
        // ------------- col-major path: s = 0,1,2 -------------
        const int c0 = (unit - 8) << 6;
        const float* bp = v + ((size_t)row << 16) + c0 + l;   // lane -> column

        #pragma unroll
        for (int m = 0; m < 8; ++m) {
            const int u0 = 32 * wv + 4 * m;                    // wave covers 32 u's
            H4 p;
            p.h[0] = (_Float16)bp[(u0 + 0) * 512];
            p.h[1] = (_Float16)bp[(u0 + 1) * 512];
            p.h[2] = (_Float16)bp[(u0 + 2) * 512];
            p.h[3] = (_Float16)bp[(u0 + 3) * 512];
            *(uint2*)&sh16[l * 128 + (u0 ^ (8 * (l & 15)))] = p.q;  // b64, conflict-free
        }
        __syncthreads();

        // schedule: w0: s0; w1: s1; w2: s2[0,8); w3: s2[8,16)
        if (wv == 0) {          // s=0: window = u-bits 3..6
            f32x4 acc = {0.f, 0.f, 0.f, 0.f};
            #pragma unroll
            for (int cc = 0; cc < 16; ++cc) {
                const int cl = 4 * cc + h;
                const f16x8 f = *(const f16x8*)&sh16[cl * 128 + ((8 * i) ^ (8 * (cl & 15)))];
                acc = MFMAH(f, f, acc);
            }
            contract16(Wl, acc, i, h, l, &accrow[0]);
        } else if (wv == 1) {   // s=1 full
            f32x4 acc = {0.f, 0.f, 0.f, 0.f};
            #pragma unroll
            for (int cc = 0; cc < 16; ++cc) {
                const int cl = 4 * cc + h;
                const int k = 8 * (cl & 15);
                Frag fr;
                fr.q[0] = *(const uint2*)&sh16[cl * 128 + ((4 * i) ^ k)];
                fr.q[1] = *(const uint2*)&sh16[cl * 128 + ((64 + 4 * i) ^ k)];
                acc = MFMAH(fr.v, fr.v, acc);
            }
            contract16(Wl, acc, i, h, l, &accrow[1]);
        } else if (wv == 2) {   // s=2 head
            f32x4 acc = {0.f, 0.f, 0.f, 0.f};
            #pragma unroll
            for (int cc = 0; cc < 8; ++cc) {
                const int cl = 4 * cc + h;
                const int k = 8 * (cl & 15);
                Frag fr;
                #pragma unroll
                for (int p = 0; p < 4; ++p)
                    fr.w[p] = *(const unsigned int*)&sh16[cl * 128 + ((2 * i + 32 * p) ^ k)];
                acc = MFMAH(fr.v, fr.v, acc);
            }
            contract16(Wl, acc, i, h, l, &accrow[2]);
        } else {                // s=2 tail
            f32x4 acc = {0.f, 0.f, 0.f, 0.f};
            #pragma unroll
            for (int cc = 8; cc < 16; ++cc) {
                const int cl = 4 * cc + h;
                const int k = 8 * (cl & 15);
                Frag fr;
                #pragma unroll
                for (int p = 0; p < 4; ++p)
                    fr.w[p] = *(const unsigned int*)&sh16[cl * 128 + ((2 * i + 32 * p) ^ k)];
                acc = MFMAH(fr.v, fr.v, acc);
            }
            contract16(Wl, acc, i, h, l, &accrow[2]);
        }
    }
}

__global__ __launch_bounds__(256) void finalize_kernel(const float* __restrict__ acc,
                                                       float* __restrict__ out) {
    const int idx = blockIdx.x * 256 + threadIdx.x;
    if (idx < 512 * 13) {
        const int row = idx / 13, s = idx % 13;
        out[idx] = acc[row * 14 + s] / acc[row * 14 + 13];
    }
}

extern "C" void kernel_launch(void* const* d_in, const int* in_sizes, int n_in,
                              void* d_out, int out_size, void* d_ws, size_t ws_size,
                              hipStream_t stream) {
    const float* vb = (const float*)d_in[0];
    const float* wt = (const float*)d_in[1];
    float* out = (float*)d_out;
    float* ws = (float*)d_ws;
    float* acc = ws + 256;

    setup_kernel<<<1, 256, 0, stream>>>(wt, ws);
    main_kernel<<<8192, 256, 0, stream>>>(vb, ws, acc);
    finalize_kernel<<<26, 256, 0, stream>>>(acc, out);
}